// Round 9
// baseline (29.037 us; speedup 1.0000x reference)
//
#include <hip/hip_runtime.h>

#define NEI 16
#define KK 4
#define DIN 64
#define DOUT 64
#define WPB 4
#define BLK (WPB * 64)
#define MAXBLOCKS 2048
#define WLOFF 64  // worklist payload starts at wl[WLOFF]

__device__ __forceinline__ float wave_bcast_sum(float v) {
#pragma unroll
  for (int s = 1; s < 64; s <<= 1) v += __shfl_xor(v, s, 64);
  return v;
}

__device__ __forceinline__ float artanh_c(float z) {
  z = fminf(z, 1.0f - 1e-7f);
  z = fmaxf(z, -1.0f + 1e-7f);
  return atanhf(z);
}

__device__ __forceinline__ float tanh_fast(float r) {
  const float e = __expf(2.f * r);
  return (e - 1.f) / (e + 1.f);
}

__device__ __forceinline__ float cosh_fast(float t) {
  const float e = __expf(t);
  return 0.5f * (e + 1.f / e);
}

// ---------------- Phase A: lean pregate, max occupancy ----------------
// wave = point; lane = (nn = lane>>2, q = lane&3). Zero-store everyone;
// push pregate-passing points to worklist. No heavy math in this kernel,
// so VGPR stays low and 6 waves/SIMD are resident.
__global__ __launch_bounds__(BLK, 6) void kpa_gate(
    const float* __restrict__ x, const int* __restrict__ nei,
    const float* __restrict__ kt, float* __restrict__ out,
    int* __restrict__ wl, int npts) {
  __shared__ float sAT[KK];
  const int tid = threadIdx.x, wv = tid >> 6, lane = tid & 63;
  {
    float v = kt[wv * DIN + lane];
    float n2 = wave_bcast_sum(v * v);
    if (lane == 0) sAT[wv] = sqrtf(fmaxf(n2, 1e-14f));  // artanh|xk| = |kt|
  }
  __syncthreads();
  const float maxAT = fmaxf(fmaxf(sAT[0], sAT[1]), fmaxf(sAT[2], sAT[3]));
  // dist(x,y) < 0.66+2*maxAT (+0.02 margin) <=> |x-y|^2 < Cthr*(1-x2)*(1-y2)
  const float Cthr = 0.5f * (cosh_fast(0.68f + 2.f * maxAT) - 1.f);

  const int b = blockIdx.x * WPB + wv;
  if (b >= npts) return;
  const int nn = lane >> 2, q = lane & 3;
  const int j = nei[b * NEI + nn];

  out[(size_t)b * DOUT + lane] = 0.f;  // default; phase B overwrites active pts

  const float4* yr = reinterpret_cast<const float4*>(x + (size_t)j * DIN);
  const float4* xr = reinterpret_cast<const float4*>(x + (size_t)b * DIN);
  float xy = 0.f, y2 = 0.f, x2 = 0.f;
#pragma unroll
  for (int c = 0; c < 4; ++c) {
    const float4 yv = yr[c * 4 + q];  // segment-minimal interleave (R7)
    const float4 xv = xr[c * 4 + q];
    xy = fmaf(yv.x, xv.x, xy); xy = fmaf(yv.y, xv.y, xy);
    xy = fmaf(yv.z, xv.z, xy); xy = fmaf(yv.w, xv.w, xy);
    y2 = fmaf(yv.x, yv.x, y2); y2 = fmaf(yv.y, yv.y, y2);
    y2 = fmaf(yv.z, yv.z, y2); y2 = fmaf(yv.w, yv.w, y2);
    x2 = fmaf(xv.x, xv.x, x2); x2 = fmaf(xv.y, xv.y, x2);
    x2 = fmaf(xv.z, xv.z, x2); x2 = fmaf(xv.w, xv.w, x2);
  }
#pragma unroll
  for (int s = 1; s < 4; s <<= 1) {
    xy += __shfl_xor(xy, s, 64);
    y2 += __shfl_xor(y2, s, 64);
    x2 += __shfl_xor(x2, s, 64);
  }
  const float e2 = fmaxf(x2 - 2.f * xy + y2, 0.f);
  const bool nearp = e2 < Cthr * (1.f - x2) * (1.f - y2);
  if (__ballot(nearp) != 0ull && lane == 0) {
    const int idx = atomicAdd(wl, 1);
    wl[WLOFF + idx] = b;
  }
}

// ---------------- Phase B: worklist-driven heavy pass ----------------
// Fixed small grid; grid-strides over worklist (usually empty -> exits fast).
__global__ __launch_bounds__(BLK) void kpa_heavy(
    const float* __restrict__ x, const int* __restrict__ nei,
    const float* __restrict__ nmask, const float* __restrict__ Wg,
    const float* __restrict__ bias, const float* __restrict__ kt,
    const int* __restrict__ wl, float* __restrict__ out, int npts) {
  __shared__ __align__(16) float sXK[KK][DIN];
  __shared__ __align__(16) float sEB[KK][DOUT];
  __shared__ float sXK2[KK], sEB2[KK];
  __shared__ __align__(16) float sUv[WPB][DIN];

  const int tid = threadIdx.x, wv = tid >> 6, lane = tid & 63;
  {
    float v = kt[wv * DIN + lane];
    float bv = bias[wv * DOUT + lane];
    float n2 = wave_bcast_sum(v * v);
    float nr = sqrtf(fmaxf(n2, 1e-14f));
    float t = tanh_fast(nr);
    sXK[wv][lane] = t / nr * v;
    float bn2 = wave_bcast_sum(bv * bv);
    float bnr = sqrtf(fmaxf(bn2, 1e-14f));
    float tb = tanh_fast(bnr);
    sEB[wv][lane] = tb / bnr * bv;
    if (lane == 0) {
      sXK2[wv] = t * t;
      sEB2[wv] = tb * tb;
    }
  }
  __syncthreads();

  const int cnt = wl[0];
  const int nn = lane >> 2, q = lane & 3, kme = lane & 3;
  const int stride = gridDim.x * WPB;

  for (int i = blockIdx.x * WPB + wv; i < cnt; i += stride) {
    const int b = wl[WLOFF + i];
    const int jc = nei[b * NEI + nn];
    const float mskme = nmask[b * NEI + nn];

    float4 yc[4], xc[4];
    {
      const float4* yr = reinterpret_cast<const float4*>(x + (size_t)jc * DIN);
      const float4* xr = reinterpret_cast<const float4*>(x + (size_t)b * DIN);
#pragma unroll
      for (int c = 0; c < 4; ++c) {
        xc[c] = xr[c * 4 + q];
        yc[c] = yr[c * 4 + q];
      }
    }
    float xy = 0.f, y2 = 0.f, x2 = 0.f;
    float dk[KK] = {0.f, 0.f, 0.f, 0.f};
    float pk[KK] = {0.f, 0.f, 0.f, 0.f};
#pragma unroll
    for (int c = 0; c < 4; ++c) {
      xy = fmaf(yc[c].x, xc[c].x, xy); xy = fmaf(yc[c].y, xc[c].y, xy);
      xy = fmaf(yc[c].z, xc[c].z, xy); xy = fmaf(yc[c].w, xc[c].w, xy);
      y2 = fmaf(yc[c].x, yc[c].x, y2); y2 = fmaf(yc[c].y, yc[c].y, y2);
      y2 = fmaf(yc[c].z, yc[c].z, y2); y2 = fmaf(yc[c].w, yc[c].w, y2);
      x2 = fmaf(xc[c].x, xc[c].x, x2); x2 = fmaf(xc[c].y, xc[c].y, x2);
      x2 = fmaf(xc[c].z, xc[c].z, x2); x2 = fmaf(xc[c].w, xc[c].w, x2);
    }
#pragma unroll
    for (int k = 0; k < KK; ++k) {
      const float4* xkp = reinterpret_cast<const float4*>(&sXK[k][0]);
#pragma unroll
      for (int c = 0; c < 4; ++c) {
        const float4 xk4 = xkp[c * 4 + q];
        dk[k] = fmaf(yc[c].x, xk4.x, dk[k]); dk[k] = fmaf(yc[c].y, xk4.y, dk[k]);
        dk[k] = fmaf(yc[c].z, xk4.z, dk[k]); dk[k] = fmaf(yc[c].w, xk4.w, dk[k]);
        pk[k] = fmaf(xc[c].x, xk4.x, pk[k]); pk[k] = fmaf(xc[c].y, xk4.y, pk[k]);
        pk[k] = fmaf(xc[c].z, xk4.z, pk[k]); pk[k] = fmaf(xc[c].w, xk4.w, pk[k]);
      }
    }
#pragma unroll
    for (int s = 1; s < 4; s <<= 1) {
      xy += __shfl_xor(xy, s, 64);
      y2 += __shfl_xor(y2, s, 64);
      x2 += __shfl_xor(x2, s, 64);
#pragma unroll
      for (int k = 0; k < KK; ++k) {
        dk[k] += __shfl_xor(dk[k], s, 64);
        pk[k] += __shfl_xor(pk[k], s, 64);
      }
    }

    // exact gate (identical math to round 7)
    const float Bc = 1.f - x2;
    const float A = 1.f - 2.f * xy + y2;
    const float den = fmaxf(1.f - 2.f * xy + x2 * y2, 1e-15f);
    const float inv = 1.f / den;
    const float num2 = fmaxf(A * A * x2 - 2.f * A * Bc * xy + Bc * Bc * y2, 0.f);
    const float nm2 = num2 * inv * inv;
    const float nmr = sqrtf(fmaxf(nm2, 1e-14f));
    const float scl = (nmr > 0.99999f) ? (0.99999f / nmr) : 1.f;
    const float fac = inv * scl;
    const float n02 = nm2 * scl * scl;
    const float B2 = 1.f - n02;
    const float dd = fac * (Bc * dk[kme] - A * pk[kme]);
    const float xk2 = sXK2[kme];
    const float A2 = 1.f - 2.f * dd + xk2;
    const float dn2 = fmaxf(1.f - 2.f * dd + n02 * xk2, 1e-15f);
    const float nu2 = fmaxf(A2 * A2 * n02 - 2.f * A2 * B2 * dd + B2 * B2 * xk2, 0.f);
    const float mm2 = nu2 / (dn2 * dn2);
    float w = 0.f;
    if (mm2 < 0.101505f && mskme > 0.f) {
      const float dis = 2.f * artanh_c(sqrtf(fmaxf(mm2, 1e-14f)));
      w = fmaxf(1.f - dis * (1.0f / 0.66f), 0.f) * mskme;
    }
    const unsigned long long act = __ballot(w > 0.f);
    if (act == 0ull) {
      out[(size_t)b * DOUT + lane] = 0.f;  // same as phase A default
      continue;
    }

    const float xbd = x[(size_t)b * DIN + lane];
    float midv[KK];
#pragma unroll
    for (int k = 0; k < KK; ++k) {
      float macc = 0.f, wsm = 0.f;
      unsigned long long m = act & (0x1111111111111111ull << k);
      const float ebt = sEB[k][lane];
      const float eb2 = sEB2[k];
      while (m) {
        const int g = __ffsll(m) - 1;
        m &= m - 1;
        const float wn = __shfl(w, g, 64);
        const float fac_n = __shfl(fac, g, 64);
        const float A_n = __shfl(A, g, 64);
        const float n02_n = __shfl(n02, g, 64);
        const int j_n = __shfl(jc, g, 64);
        const float yd = x[(size_t)j_n * DIN + lane];
        const float x0t = fac_n * (Bc * yd - A_n * xbd);
        const float n0 = sqrtf(fmaxf(n02_n, 1e-14f));
        const float al = artanh_c(n0) / n0;
        asm volatile("s_waitcnt lgkmcnt(0)" ::: "memory");
        sUv[wv][lane] = al * x0t;  // u = logmap0(x0)
        asm volatile("s_waitcnt lgkmcnt(0)" ::: "memory");
        __builtin_amdgcn_sched_barrier(0);
        float a0 = 0.f, a1 = 0.f, a2 = 0.f, a3 = 0.f;
        const float4* wrow = reinterpret_cast<const float4*>(Wg) + ((k * DOUT + lane) << 4);
        const float4* urow = reinterpret_cast<const float4*>(&sUv[wv][0]);
#pragma unroll
        for (int g4 = 0; g4 < 16; ++g4) {
          const float4 w4 = wrow[g4];
          const float4 u4 = urow[g4];
          a0 = fmaf(w4.x, u4.x, a0);
          a1 = fmaf(w4.y, u4.y, a1);
          a2 = fmaf(w4.z, u4.z, a2);
          a3 = fmaf(w4.w, u4.w, a3);
        }
        const float hpre = (a0 + a1) + (a2 + a3);
        const float nh2 = wave_bcast_sum(hpre * hpre);
        const float nh = sqrtf(fmaxf(nh2, 1e-14f));
        const float sh = tanhf(nh) / nh;
        const float ht = sh * hpre;
        const float hx2 = sh * sh * nh2;
        const float hxy = wave_bcast_sum(ht * ebt);
        const float A3 = 1.f + 2.f * hxy + eb2;
        const float B3 = 1.f - hx2;
        const float dn3 = fmaxf(1.f + 2.f * hxy + hx2 * eb2, 1e-15f);
        float hm = (A3 * ht + B3 * ebt) / dn3;
        float n2h = wave_bcast_sum(hm * hm);
        const float nnh = sqrtf(fmaxf(n2h, 1e-14f));
        if (nnh > 0.99999f) {
          const float s = 0.99999f / nnh;
          hm *= s;
          n2h *= s * s;
        }
        const float ip = 1.f / (1.f + n2h);
        const float kx = 2.f * hm * ip;
        const float kx2 = 4.f * n2h * ip * ip;
        const float gam = 1.f / sqrtf(fmaxf(1.f - kx2, 1e-7f));
        const float wgv = wn * gam;
        macc = fmaf(wgv, kx, macc);
        wsm += wgv;
      }
      midv[k] = macc / fmaxf(wsm, 1e-10f);
    }

    float m2v[KK];
#pragma unroll
    for (int k = 0; k < KK; ++k) m2v[k] = midv[k] * midv[k];
#pragma unroll
    for (int s = 1; s < 64; s <<= 1) {
#pragma unroll
      for (int k = 0; k < KK; ++k) m2v[k] += __shfl_xor(m2v[k], s, 64);
    }
    float onum = 0.f, oden = 0.f;
#pragma unroll
    for (int k = 0; k < KK; ++k) {
      const float g = 1.f / sqrtf(fmaxf(1.f - m2v[k], 1e-7f));
      onum = fmaf(g, midv[k], onum);
      oden += g;
    }
    const float ok = onum / fmaxf(oden, 1e-10f);
    const float no2 = wave_bcast_sum(ok * ok);
    float p = ok / (1.f + sqrtf(fmaxf(1.f - no2, 1e-7f)));
    float np2 = wave_bcast_sum(p * p);
    float npn = sqrtf(fmaxf(np2, 1e-14f));
    if (npn > 0.99999f) {
      p *= 0.99999f / npn;
      npn = 0.99999f;
    }
    const float al2 = artanh_c(npn) / npn;
    const float rr = fmaxf(al2 * p, 0.f);
    const float nr2 = wave_bcast_sum(rr * rr);
    const float nrr = sqrtf(fmaxf(nr2, 1e-14f));
    out[(size_t)b * DOUT + lane] = tanhf(nrr) / nrr * rr;
  }
}

// ---------------- fallback: round-7 monolithic (no-workspace path) ----------------
__global__ __launch_bounds__(BLK) void kpa_fused(
    const float* __restrict__ x, const int* __restrict__ nei,
    const float* __restrict__ nmask, const float* __restrict__ Wg,
    const float* __restrict__ bias, const float* __restrict__ kt,
    float* __restrict__ out, int npts) {
  __shared__ __align__(16) float sXK[KK][DIN];
  __shared__ __align__(16) float sEB[KK][DOUT];
  __shared__ float sXK2[KK], sEB2[KK], sAT[KK];
  __shared__ __align__(16) float sUv[WPB][DIN];

  const int tid = threadIdx.x, wv = tid >> 6, lane = tid & 63;
  {
    float v = kt[wv * DIN + lane];
    float bv = bias[wv * DOUT + lane];
    float n2 = wave_bcast_sum(v * v);
    float nr = sqrtf(fmaxf(n2, 1e-14f));
    float t = tanh_fast(nr);
    sXK[wv][lane] = t / nr * v;
    float bn2 = wave_bcast_sum(bv * bv);
    float bnr = sqrtf(fmaxf(bn2, 1e-14f));
    float tb = tanh_fast(bnr);
    sEB[wv][lane] = tb / bnr * bv;
    if (lane == 0) {
      sXK2[wv] = t * t;
      sEB2[wv] = tb * tb;
      sAT[wv] = nr;
    }
  }
  __syncthreads();

  const float maxAT = fmaxf(fmaxf(sAT[0], sAT[1]), fmaxf(sAT[2], sAT[3]));
  const float Cthr = 0.5f * (cosh_fast(0.68f + 2.f * maxAT) - 1.f);
  const int nn = lane >> 2, q = lane & 3, kme = lane & 3;
  const int stride = gridDim.x * WPB;

  for (int b = blockIdx.x * WPB + wv; b < npts; b += stride) {
    const int jc = nei[b * NEI + nn];
    float4 yc[4], xc[4];
    {
      const float4* yr = reinterpret_cast<const float4*>(x + (size_t)jc * DIN);
      const float4* xr = reinterpret_cast<const float4*>(x + (size_t)b * DIN);
#pragma unroll
      for (int c = 0; c < 4; ++c) {
        xc[c] = xr[c * 4 + q];
        yc[c] = yr[c * 4 + q];
      }
    }
    float xy = 0.f, y2 = 0.f, x2 = 0.f;
#pragma unroll
    for (int c = 0; c < 4; ++c) {
      xy = fmaf(yc[c].x, xc[c].x, xy); xy = fmaf(yc[c].y, xc[c].y, xy);
      xy = fmaf(yc[c].z, xc[c].z, xy); xy = fmaf(yc[c].w, xc[c].w, xy);
      y2 = fmaf(yc[c].x, yc[c].x, y2); y2 = fmaf(yc[c].y, yc[c].y, y2);
      y2 = fmaf(yc[c].z, yc[c].z, y2); y2 = fmaf(yc[c].w, yc[c].w, y2);
      x2 = fmaf(xc[c].x, xc[c].x, x2); x2 = fmaf(xc[c].y, xc[c].y, x2);
      x2 = fmaf(xc[c].w, xc[c].w, x2); x2 = fmaf(xc[c].z, xc[c].z, x2);
    }
#pragma unroll
    for (int s = 1; s < 4; s <<= 1) {
      xy += __shfl_xor(xy, s, 64);
      y2 += __shfl_xor(y2, s, 64);
      x2 += __shfl_xor(x2, s, 64);
    }
    const float e2 = fmaxf(x2 - 2.f * xy + y2, 0.f);
    const bool nearp = e2 < Cthr * (1.f - x2) * (1.f - y2);
    if (__ballot(nearp) == 0ull) {
      out[(size_t)b * DOUT + lane] = 0.f;
      continue;
    }
    const float Bc = 1.f - x2;
    const float A = 1.f - 2.f * xy + y2;
    const float den = fmaxf(1.f - 2.f * xy + x2 * y2, 1e-15f);
    const float inv = 1.f / den;
    const float num2 = fmaxf(A * A * x2 - 2.f * A * Bc * xy + Bc * Bc * y2, 0.f);
    const float nm2 = num2 * inv * inv;
    const float mskme = nmask[b * NEI + nn];
    float dk[KK] = {0.f, 0.f, 0.f, 0.f};
    float pk[KK] = {0.f, 0.f, 0.f, 0.f};
#pragma unroll
    for (int k = 0; k < KK; ++k) {
      const float4* xkp = reinterpret_cast<const float4*>(&sXK[k][0]);
#pragma unroll
      for (int c = 0; c < 4; ++c) {
        const float4 xk4 = xkp[c * 4 + q];
        dk[k] = fmaf(yc[c].x, xk4.x, dk[k]); dk[k] = fmaf(yc[c].y, xk4.y, dk[k]);
        dk[k] = fmaf(yc[c].z, xk4.z, dk[k]); dk[k] = fmaf(yc[c].w, xk4.w, dk[k]);
        pk[k] = fmaf(xc[c].x, xk4.x, pk[k]); pk[k] = fmaf(xc[c].y, xk4.y, pk[k]);
        pk[k] = fmaf(xc[c].z, xk4.z, pk[k]); pk[k] = fmaf(xc[c].w, xk4.w, pk[k]);
      }
    }
#pragma unroll
    for (int s = 1; s < 4; s <<= 1) {
#pragma unroll
      for (int k = 0; k < KK; ++k) {
        dk[k] += __shfl_xor(dk[k], s, 64);
        pk[k] += __shfl_xor(pk[k], s, 64);
      }
    }
    const float nmr = sqrtf(fmaxf(nm2, 1e-14f));
    const float scl = (nmr > 0.99999f) ? (0.99999f / nmr) : 1.f;
    const float fac = inv * scl;
    const float n02 = nm2 * scl * scl;
    const float B2 = 1.f - n02;
    const float dd = fac * (Bc * dk[kme] - A * pk[kme]);
    const float xk2 = sXK2[kme];
    const float A2 = 1.f - 2.f * dd + xk2;
    const float dn2 = fmaxf(1.f - 2.f * dd + n02 * xk2, 1e-15f);
    const float nu2 = fmaxf(A2 * A2 * n02 - 2.f * A2 * B2 * dd + B2 * B2 * xk2, 0.f);
    const float mm2 = nu2 / (dn2 * dn2);
    float w = 0.f;
    if (mm2 < 0.101505f && mskme > 0.f) {
      const float dis = 2.f * artanh_c(sqrtf(fmaxf(mm2, 1e-14f)));
      w = fmaxf(1.f - dis * (1.0f / 0.66f), 0.f) * mskme;
    }
    const unsigned long long act = __ballot(w > 0.f);
    if (act == 0ull) {
      out[(size_t)b * DOUT + lane] = 0.f;
      continue;
    }
    const float xbd = x[(size_t)b * DIN + lane];
    float midv[KK];
#pragma unroll
    for (int k = 0; k < KK; ++k) {
      float macc = 0.f, wsm = 0.f;
      unsigned long long m = act & (0x1111111111111111ull << k);
      const float ebt = sEB[k][lane];
      const float eb2 = sEB2[k];
      while (m) {
        const int g = __ffsll(m) - 1;
        m &= m - 1;
        const float wn = __shfl(w, g, 64);
        const float fac_n = __shfl(fac, g, 64);
        const float A_n = __shfl(A, g, 64);
        const float n02_n = __shfl(n02, g, 64);
        const int j_n = __shfl(jc, g, 64);
        const float yd = x[(size_t)j_n * DIN + lane];
        const float x0t = fac_n * (Bc * yd - A_n * xbd);
        const float n0 = sqrtf(fmaxf(n02_n, 1e-14f));
        const float al = artanh_c(n0) / n0;
        asm volatile("s_waitcnt lgkmcnt(0)" ::: "memory");
        sUv[wv][lane] = al * x0t;
        asm volatile("s_waitcnt lgkmcnt(0)" ::: "memory");
        __builtin_amdgcn_sched_barrier(0);
        float a0 = 0.f, a1 = 0.f, a2 = 0.f, a3 = 0.f;
        const float4* wrow = reinterpret_cast<const float4*>(Wg) + ((k * DOUT + lane) << 4);
        const float4* urow = reinterpret_cast<const float4*>(&sUv[wv][0]);
#pragma unroll
        for (int g4 = 0; g4 < 16; ++g4) {
          const float4 w4 = wrow[g4];
          const float4 u4 = urow[g4];
          a0 = fmaf(w4.x, u4.x, a0);
          a1 = fmaf(w4.y, u4.y, a1);
          a2 = fmaf(w4.z, u4.z, a2);
          a3 = fmaf(w4.w, u4.w, a3);
        }
        const float hpre = (a0 + a1) + (a2 + a3);
        const float nh2 = wave_bcast_sum(hpre * hpre);
        const float nh = sqrtf(fmaxf(nh2, 1e-14f));
        const float sh = tanhf(nh) / nh;
        const float ht = sh * hpre;
        const float hx2 = sh * sh * nh2;
        const float hxy = wave_bcast_sum(ht * ebt);
        const float A3 = 1.f + 2.f * hxy + eb2;
        const float B3 = 1.f - hx2;
        const float dn3 = fmaxf(1.f + 2.f * hxy + hx2 * eb2, 1e-15f);
        float hm = (A3 * ht + B3 * ebt) / dn3;
        float n2h = wave_bcast_sum(hm * hm);
        const float nnh = sqrtf(fmaxf(n2h, 1e-14f));
        if (nnh > 0.99999f) {
          const float s = 0.99999f / nnh;
          hm *= s;
          n2h *= s * s;
        }
        const float ip = 1.f / (1.f + n2h);
        const float kx = 2.f * hm * ip;
        const float kx2 = 4.f * n2h * ip * ip;
        const float gam = 1.f / sqrtf(fmaxf(1.f - kx2, 1e-7f));
        const float wgv = wn * gam;
        macc = fmaf(wgv, kx, macc);
        wsm += wgv;
      }
      midv[k] = macc / fmaxf(wsm, 1e-10f);
    }
    float m2v[KK];
#pragma unroll
    for (int k = 0; k < KK; ++k) m2v[k] = midv[k] * midv[k];
#pragma unroll
    for (int s = 1; s < 64; s <<= 1) {
#pragma unroll
      for (int k = 0; k < KK; ++k) m2v[k] += __shfl_xor(m2v[k], s, 64);
    }
    float onum = 0.f, oden = 0.f;
#pragma unroll
    for (int k = 0; k < KK; ++k) {
      const float g = 1.f / sqrtf(fmaxf(1.f - m2v[k], 1e-7f));
      onum = fmaf(g, midv[k], onum);
      oden += g;
    }
    const float ok = onum / fmaxf(oden, 1e-10f);
    const float no2 = wave_bcast_sum(ok * ok);
    float p = ok / (1.f + sqrtf(fmaxf(1.f - no2, 1e-7f)));
    float np2 = wave_bcast_sum(p * p);
    float npn = sqrtf(fmaxf(np2, 1e-14f));
    if (npn > 0.99999f) {
      p *= 0.99999f / npn;
      npn = 0.99999f;
    }
    const float al2 = artanh_c(npn) / npn;
    const float rr = fmaxf(al2 * p, 0.f);
    const float nr2 = wave_bcast_sum(rr * rr);
    const float nrr = sqrtf(fmaxf(nr2, 1e-14f));
    out[(size_t)b * DOUT + lane] = tanhf(nrr) / nrr * rr;
  }
}

extern "C" void kernel_launch(void* const* d_in, const int* in_sizes, int n_in,
                              void* d_out, int out_size, void* d_ws, size_t ws_size,
                              hipStream_t stream) {
  const float* x = (const float*)d_in[0];
  const int* nei = (const int*)d_in[1];
  const float* nmask = (const float*)d_in[2];
  const float* W = (const float*)d_in[3];
  const float* bias = (const float*)d_in[4];
  const float* kt = (const float*)d_in[5];
  float* out = (float*)d_out;

  const int npts = in_sizes[0] / DIN;
  const size_t need = ((size_t)WLOFF + (size_t)npts) * sizeof(int);

  if (d_ws != nullptr && ws_size >= need) {
    int* wl = (int*)d_ws;
    hipMemsetAsync(wl, 0, sizeof(int), stream);  // reset worklist counter
    const int gridA = (npts + WPB - 1) / WPB;
    kpa_gate<<<gridA, BLK, 0, stream>>>(x, nei, kt, out, wl, npts);
    kpa_heavy<<<128, BLK, 0, stream>>>(x, nei, nmask, W, bias, kt, wl, out, npts);
  } else {
    int grid = (npts + WPB - 1) / WPB;
    if (grid > MAXBLOCKS) grid = MAXBLOCKS;
    kpa_fused<<<grid, BLK, 0, stream>>>(x, nei, nmask, W, bias, kt, out, npts);
  }
}

// Round 10
// 26.982 us; speedup vs baseline: 1.0762x; 1.0762x over previous
//
#include <hip/hip_runtime.h>
#include <hip/hip_fp16.h>

#define NEI 16
#define KK 4
#define DIN 64
#define DOUT 64
#define WPB 4
#define BLK (WPB * 64)
#define MAXBLOCKS 2048

__device__ __forceinline__ float wave_bcast_sum(float v) {
#pragma unroll
  for (int s = 1; s < 64; s <<= 1) v += __shfl_xor(v, s, 64);
  return v;
}

__device__ __forceinline__ float artanh_c(float z) {
  z = fminf(z, 1.0f - 1e-7f);
  z = fmaxf(z, -1.0f + 1e-7f);
  return atanhf(z);
}

__device__ __forceinline__ float tanh_fast(float r) {
  const float e = __expf(2.f * r);
  return (e - 1.f) / (e + 1.f);
}

__device__ __forceinline__ float cosh_fast(float t) {
  const float e = __expf(t);
  return 0.5f * (e + 1.f / e);
}

// ---------- prologue: xh = fp16(x) (2.5 MB, L2-resident) + exact n2 ----------
__global__ __launch_bounds__(BLK) void kpa_prep(const float* __restrict__ x,
                                                __half* __restrict__ xh,
                                                float* __restrict__ n2, int npts) {
  const int wv = threadIdx.x >> 6, lane = threadIdx.x & 63;
  const int stride = gridDim.x * WPB;
  for (int b = blockIdx.x * WPB + wv; b < npts; b += stride) {
    const float v = x[(size_t)b * DIN + lane];
    xh[(size_t)b * DIN + lane] = __float2half(v);
    float s = v * v;
#pragma unroll
    for (int sh = 1; sh < 64; sh <<= 1) s += __shfl_xor(s, sh, 64);
    if (lane == 0) n2[b] = s;
  }
}

// ---------- main: fp16 pregate (gather 128B/row from 2.5MB table) ----------
// lane = (nn = lane>>2, q = lane&3); quad covers the 64 dims via 2 x 16B chunks.
// pregate: e2 < Cthr*(1-x2)*(1-y2) + EPS, EPS=0.01 >> fp16 dot error (<=1.3e-3).
// Admitted points run the exact fp32 path (identical math to round 7).
__global__ __launch_bounds__(BLK) void kpa_main(
    const float* __restrict__ x, const int* __restrict__ nei,
    const float* __restrict__ nmask, const float* __restrict__ Wg,
    const float* __restrict__ bias, const float* __restrict__ kt,
    const __half* __restrict__ xh, const float* __restrict__ n2,
    float* __restrict__ out, int npts) {
  __shared__ __align__(16) float sXK[KK][DIN];
  __shared__ __align__(16) float sEB[KK][DOUT];
  __shared__ float sXK2[KK], sEB2[KK], sAT[KK];
  __shared__ __align__(16) float sUv[WPB][DIN];

  const int tid = threadIdx.x, wv = tid >> 6, lane = tid & 63;
  {
    float v = kt[wv * DIN + lane];
    float bv = bias[wv * DOUT + lane];
    float nn2 = wave_bcast_sum(v * v);
    float nr = sqrtf(fmaxf(nn2, 1e-14f));
    float t = tanh_fast(nr);
    sXK[wv][lane] = t / nr * v;
    float bn2 = wave_bcast_sum(bv * bv);
    float bnr = sqrtf(fmaxf(bn2, 1e-14f));
    float tb = tanh_fast(bnr);
    sEB[wv][lane] = tb / bnr * bv;
    if (lane == 0) {
      sXK2[wv] = t * t;
      sEB2[wv] = tb * tb;
      sAT[wv] = nr;  // artanh|x_kernel| = |kt|
    }
  }
  __syncthreads();

  const float maxAT = fmaxf(fmaxf(sAT[0], sAT[1]), fmaxf(sAT[2], sAT[3]));
  const float Cthr = 0.5f * (cosh_fast(0.68f + 2.f * maxAT) - 1.f);

  const int nn = lane >> 2, q = lane & 3, kme = lane & 3;
  const int stride = gridDim.x * WPB;

  for (int b = blockIdx.x * WPB + wv; b < npts; b += stride) {
    const int jc = nei[b * NEI + nn];

    // fp16 dot x.y over this lane's 16 dims (2 x 16B chunks, segment-minimal)
    const float4* yr = reinterpret_cast<const float4*>(xh + (size_t)jc * DIN);
    const float4* xr = reinterpret_cast<const float4*>(xh + (size_t)b * DIN);
    float xy = 0.f;
#pragma unroll
    for (int c = 0; c < 2; ++c) {
      const float4 yv = yr[c * 4 + q];
      const float4 xv = xr[c * 4 + q];
#pragma unroll
      for (int t = 0; t < 4; ++t) {
        const float yw = (t == 0) ? yv.x : (t == 1) ? yv.y : (t == 2) ? yv.z : yv.w;
        const float xw = (t == 0) ? xv.x : (t == 1) ? xv.y : (t == 2) ? xv.z : xv.w;
        const float2 fy = __half22float2(__builtin_bit_cast(__half2, yw));
        const float2 fx = __half22float2(__builtin_bit_cast(__half2, xw));
        xy = fmaf(fy.x, fx.x, xy);
        xy = fmaf(fy.y, fx.y, xy);
      }
    }
#pragma unroll
    for (int s = 1; s < 4; s <<= 1) xy += __shfl_xor(xy, s, 64);

    const float x2e = n2[b];
    const float y2e = n2[jc];
    const float e2 = x2e - 2.f * xy + y2e;
    const bool nearp = e2 < Cthr * (1.f - x2e) * (1.f - y2e) + 0.01f;

    if (__ballot(nearp) == 0ull) {  // common case
      out[(size_t)b * DOUT + lane] = 0.f;
      continue;
    }

    // ---- rare path: exact fp32 (identical math to round 7) ----
    float4 yc[4], xc[4];
    {
      const float4* yrf = reinterpret_cast<const float4*>(x + (size_t)jc * DIN);
      const float4* xrf = reinterpret_cast<const float4*>(x + (size_t)b * DIN);
#pragma unroll
      for (int c = 0; c < 4; ++c) {
        xc[c] = xrf[c * 4 + q];
        yc[c] = yrf[c * 4 + q];
      }
    }
    float xyf = 0.f, y2 = 0.f, x2 = 0.f;
#pragma unroll
    for (int c = 0; c < 4; ++c) {
      xyf = fmaf(yc[c].x, xc[c].x, xyf); xyf = fmaf(yc[c].y, xc[c].y, xyf);
      xyf = fmaf(yc[c].z, xc[c].z, xyf); xyf = fmaf(yc[c].w, xc[c].w, xyf);
      y2 = fmaf(yc[c].x, yc[c].x, y2); y2 = fmaf(yc[c].y, yc[c].y, y2);
      y2 = fmaf(yc[c].z, yc[c].z, y2); y2 = fmaf(yc[c].w, yc[c].w, y2);
      x2 = fmaf(xc[c].x, xc[c].x, x2); x2 = fmaf(xc[c].y, xc[c].y, x2);
      x2 = fmaf(xc[c].z, xc[c].z, x2); x2 = fmaf(xc[c].w, xc[c].w, x2);
    }
    float dk[KK] = {0.f, 0.f, 0.f, 0.f};
    float pk[KK] = {0.f, 0.f, 0.f, 0.f};
#pragma unroll
    for (int k = 0; k < KK; ++k) {
      const float4* xkp = reinterpret_cast<const float4*>(&sXK[k][0]);
#pragma unroll
      for (int c = 0; c < 4; ++c) {
        const float4 xk4 = xkp[c * 4 + q];
        dk[k] = fmaf(yc[c].x, xk4.x, dk[k]); dk[k] = fmaf(yc[c].y, xk4.y, dk[k]);
        dk[k] = fmaf(yc[c].z, xk4.z, dk[k]); dk[k] = fmaf(yc[c].w, xk4.w, dk[k]);
        pk[k] = fmaf(xc[c].x, xk4.x, pk[k]); pk[k] = fmaf(xc[c].y, xk4.y, pk[k]);
        pk[k] = fmaf(xc[c].z, xk4.z, pk[k]); pk[k] = fmaf(xc[c].w, xk4.w, pk[k]);
      }
    }
#pragma unroll
    for (int s = 1; s < 4; s <<= 1) {
      xyf += __shfl_xor(xyf, s, 64);
      y2 += __shfl_xor(y2, s, 64);
      x2 += __shfl_xor(x2, s, 64);
#pragma unroll
      for (int k = 0; k < KK; ++k) {
        dk[k] += __shfl_xor(dk[k], s, 64);
        pk[k] += __shfl_xor(pk[k], s, 64);
      }
    }

    const float Bc = 1.f - x2;
    const float A = 1.f - 2.f * xyf + y2;
    const float den = fmaxf(1.f - 2.f * xyf + x2 * y2, 1e-15f);
    const float inv = 1.f / den;
    const float num2 = fmaxf(A * A * x2 - 2.f * A * Bc * xyf + Bc * Bc * y2, 0.f);
    const float nm2 = num2 * inv * inv;
    const float mskme = nmask[b * NEI + nn];
    const float nmr = sqrtf(fmaxf(nm2, 1e-14f));
    const float scl = (nmr > 0.99999f) ? (0.99999f / nmr) : 1.f;
    const float fac = inv * scl;
    const float n02 = nm2 * scl * scl;
    const float B2 = 1.f - n02;
    const float dd = fac * (Bc * dk[kme] - A * pk[kme]);
    const float xk2 = sXK2[kme];
    const float A2 = 1.f - 2.f * dd + xk2;
    const float dn2 = fmaxf(1.f - 2.f * dd + n02 * xk2, 1e-15f);
    const float nu2 = fmaxf(A2 * A2 * n02 - 2.f * A2 * B2 * dd + B2 * B2 * xk2, 0.f);
    const float mm2 = nu2 / (dn2 * dn2);
    float w = 0.f;
    if (mm2 < 0.101505f && mskme > 0.f) {
      const float dis = 2.f * artanh_c(sqrtf(fmaxf(mm2, 1e-14f)));
      w = fmaxf(1.f - dis * (1.0f / 0.66f), 0.f) * mskme;
    }
    const unsigned long long act = __ballot(w > 0.f);
    if (act == 0ull) {
      out[(size_t)b * DOUT + lane] = 0.f;
      continue;
    }

    const float xbd = x[(size_t)b * DIN + lane];
    float midv[KK];
#pragma unroll
    for (int k = 0; k < KK; ++k) {
      float macc = 0.f, wsm = 0.f;
      unsigned long long m = act & (0x1111111111111111ull << k);
      const float ebt = sEB[k][lane];
      const float eb2 = sEB2[k];
      while (m) {
        const int g = __ffsll(m) - 1;
        m &= m - 1;
        const float wn = __shfl(w, g, 64);
        const float fac_n = __shfl(fac, g, 64);
        const float A_n = __shfl(A, g, 64);
        const float n02_n = __shfl(n02, g, 64);
        const int j_n = __shfl(jc, g, 64);
        const float yd = x[(size_t)j_n * DIN + lane];
        const float x0t = fac_n * (Bc * yd - A_n * xbd);
        const float n0 = sqrtf(fmaxf(n02_n, 1e-14f));
        const float al = artanh_c(n0) / n0;
        asm volatile("s_waitcnt lgkmcnt(0)" ::: "memory");
        sUv[wv][lane] = al * x0t;  // u = logmap0(x0)
        asm volatile("s_waitcnt lgkmcnt(0)" ::: "memory");
        __builtin_amdgcn_sched_barrier(0);
        float a0 = 0.f, a1 = 0.f, a2 = 0.f, a3 = 0.f;
        const float4* wrow = reinterpret_cast<const float4*>(Wg) + ((k * DOUT + lane) << 4);
        const float4* urow = reinterpret_cast<const float4*>(&sUv[wv][0]);
#pragma unroll
        for (int g4 = 0; g4 < 16; ++g4) {
          const float4 w4 = wrow[g4];
          const float4 u4 = urow[g4];
          a0 = fmaf(w4.x, u4.x, a0);
          a1 = fmaf(w4.y, u4.y, a1);
          a2 = fmaf(w4.z, u4.z, a2);
          a3 = fmaf(w4.w, u4.w, a3);
        }
        const float hpre = (a0 + a1) + (a2 + a3);
        const float nh2 = wave_bcast_sum(hpre * hpre);
        const float nh = sqrtf(fmaxf(nh2, 1e-14f));
        const float sh = tanhf(nh) / nh;
        const float ht = sh * hpre;
        const float hx2 = sh * sh * nh2;
        const float hxy = wave_bcast_sum(ht * ebt);
        const float A3 = 1.f + 2.f * hxy + eb2;
        const float B3 = 1.f - hx2;
        const float dn3 = fmaxf(1.f + 2.f * hxy + hx2 * eb2, 1e-15f);
        float hm = (A3 * ht + B3 * ebt) / dn3;
        float n2h = wave_bcast_sum(hm * hm);
        const float nnh = sqrtf(fmaxf(n2h, 1e-14f));
        if (nnh > 0.99999f) {
          const float s = 0.99999f / nnh;
          hm *= s;
          n2h *= s * s;
        }
        const float ip = 1.f / (1.f + n2h);
        const float kx = 2.f * hm * ip;
        const float kx2 = 4.f * n2h * ip * ip;
        const float gam = 1.f / sqrtf(fmaxf(1.f - kx2, 1e-7f));
        const float wgv = wn * gam;
        macc = fmaf(wgv, kx, macc);
        wsm += wgv;
      }
      midv[k] = macc / fmaxf(wsm, 1e-10f);
    }

    float m2v[KK];
#pragma unroll
    for (int k = 0; k < KK; ++k) m2v[k] = midv[k] * midv[k];
#pragma unroll
    for (int s = 1; s < 64; s <<= 1) {
#pragma unroll
      for (int k = 0; k < KK; ++k) m2v[k] += __shfl_xor(m2v[k], s, 64);
    }
    float onum = 0.f, oden = 0.f;
#pragma unroll
    for (int k = 0; k < KK; ++k) {
      const float g = 1.f / sqrtf(fmaxf(1.f - m2v[k], 1e-7f));
      onum = fmaf(g, midv[k], onum);
      oden += g;
    }
    const float ok = onum / fmaxf(oden, 1e-10f);
    const float no2 = wave_bcast_sum(ok * ok);
    float p = ok / (1.f + sqrtf(fmaxf(1.f - no2, 1e-7f)));
    float np2 = wave_bcast_sum(p * p);
    float npn = sqrtf(fmaxf(np2, 1e-14f));
    if (npn > 0.99999f) {
      p *= 0.99999f / npn;
      npn = 0.99999f;
    }
    const float al2 = artanh_c(npn) / npn;
    const float rr = fmaxf(al2 * p, 0.f);
    const float nr2 = wave_bcast_sum(rr * rr);
    const float nrr = sqrtf(fmaxf(nr2, 1e-14f));
    out[(size_t)b * DOUT + lane] = tanhf(nrr) / nrr * rr;
  }
}

// ---------- fallback: round-7 monolithic (no-workspace path) ----------
__global__ __launch_bounds__(BLK) void kpa_fused(
    const float* __restrict__ x, const int* __restrict__ nei,
    const float* __restrict__ nmask, const float* __restrict__ Wg,
    const float* __restrict__ bias, const float* __restrict__ kt,
    float* __restrict__ out, int npts) {
  __shared__ __align__(16) float sXK[KK][DIN];
  __shared__ __align__(16) float sEB[KK][DOUT];
  __shared__ float sXK2[KK], sEB2[KK], sAT[KK];
  __shared__ __align__(16) float sUv[WPB][DIN];

  const int tid = threadIdx.x, wv = tid >> 6, lane = tid & 63;
  {
    float v = kt[wv * DIN + lane];
    float bv = bias[wv * DOUT + lane];
    float n2 = wave_bcast_sum(v * v);
    float nr = sqrtf(fmaxf(n2, 1e-14f));
    float t = tanh_fast(nr);
    sXK[wv][lane] = t / nr * v;
    float bn2 = wave_bcast_sum(bv * bv);
    float bnr = sqrtf(fmaxf(bn2, 1e-14f));
    float tb = tanh_fast(bnr);
    sEB[wv][lane] = tb / bnr * bv;
    if (lane == 0) {
      sXK2[wv] = t * t;
      sEB2[wv] = tb * tb;
      sAT[wv] = nr;
    }
  }
  __syncthreads();

  const float maxAT = fmaxf(fmaxf(sAT[0], sAT[1]), fmaxf(sAT[2], sAT[3]));
  const float Cthr = 0.5f * (cosh_fast(0.68f + 2.f * maxAT) - 1.f);
  const int nn = lane >> 2, q = lane & 3, kme = lane & 3;
  const int stride = gridDim.x * WPB;

  for (int b = blockIdx.x * WPB + wv; b < npts; b += stride) {
    const int jc = nei[b * NEI + nn];
    float4 yc[4], xc[4];
    {
      const float4* yr = reinterpret_cast<const float4*>(x + (size_t)jc * DIN);
      const float4* xr = reinterpret_cast<const float4*>(x + (size_t)b * DIN);
#pragma unroll
      for (int c = 0; c < 4; ++c) {
        xc[c] = xr[c * 4 + q];
        yc[c] = yr[c * 4 + q];
      }
    }
    float xy = 0.f, y2 = 0.f, x2 = 0.f;
#pragma unroll
    for (int c = 0; c < 4; ++c) {
      xy = fmaf(yc[c].x, xc[c].x, xy); xy = fmaf(yc[c].y, xc[c].y, xy);
      xy = fmaf(yc[c].z, xc[c].z, xy); xy = fmaf(yc[c].w, xc[c].w, xy);
      y2 = fmaf(yc[c].x, yc[c].x, y2); y2 = fmaf(yc[c].y, yc[c].y, y2);
      y2 = fmaf(yc[c].z, yc[c].z, y2); y2 = fmaf(yc[c].w, yc[c].w, y2);
      x2 = fmaf(xc[c].x, xc[c].x, x2); x2 = fmaf(xc[c].y, xc[c].y, x2);
      x2 = fmaf(xc[c].z, xc[c].z, x2); x2 = fmaf(xc[c].w, xc[c].w, x2);
    }
#pragma unroll
    for (int s = 1; s < 4; s <<= 1) {
      xy += __shfl_xor(xy, s, 64);
      y2 += __shfl_xor(y2, s, 64);
      x2 += __shfl_xor(x2, s, 64);
    }
    const float e2 = fmaxf(x2 - 2.f * xy + y2, 0.f);
    const bool nearp = e2 < Cthr * (1.f - x2) * (1.f - y2);
    if (__ballot(nearp) == 0ull) {
      out[(size_t)b * DOUT + lane] = 0.f;
      continue;
    }
    const float Bc = 1.f - x2;
    const float A = 1.f - 2.f * xy + y2;
    const float den = fmaxf(1.f - 2.f * xy + x2 * y2, 1e-15f);
    const float inv = 1.f / den;
    const float num2 = fmaxf(A * A * x2 - 2.f * A * Bc * xy + Bc * Bc * y2, 0.f);
    const float nm2 = num2 * inv * inv;
    const float mskme = nmask[b * NEI + nn];
    float dk[KK] = {0.f, 0.f, 0.f, 0.f};
    float pk[KK] = {0.f, 0.f, 0.f, 0.f};
#pragma unroll
    for (int k = 0; k < KK; ++k) {
      const float4* xkp = reinterpret_cast<const float4*>(&sXK[k][0]);
#pragma unroll
      for (int c = 0; c < 4; ++c) {
        const float4 xk4 = xkp[c * 4 + q];
        dk[k] = fmaf(yc[c].x, xk4.x, dk[k]); dk[k] = fmaf(yc[c].y, xk4.y, dk[k]);
        dk[k] = fmaf(yc[c].z, xk4.z, dk[k]); dk[k] = fmaf(yc[c].w, xk4.w, dk[k]);
        pk[k] = fmaf(xc[c].x, xk4.x, pk[k]); pk[k] = fmaf(xc[c].y, xk4.y, pk[k]);
        pk[k] = fmaf(xc[c].z, xk4.z, pk[k]); pk[k] = fmaf(xc[c].w, xk4.w, pk[k]);
      }
    }
#pragma unroll
    for (int s = 1; s < 4; s <<= 1) {
#pragma unroll
      for (int k = 0; k < KK; ++k) {
        dk[k] += __shfl_xor(dk[k], s, 64);
        pk[k] += __shfl_xor(pk[k], s, 64);
      }
    }
    const float nmr = sqrtf(fmaxf(nm2, 1e-14f));
    const float scl = (nmr > 0.99999f) ? (0.99999f / nmr) : 1.f;
    const float fac = inv * scl;
    const float n02 = nm2 * scl * scl;
    const float B2 = 1.f - n02;
    const float dd = fac * (Bc * dk[kme] - A * pk[kme]);
    const float xk2 = sXK2[kme];
    const float A2 = 1.f - 2.f * dd + xk2;
    const float dn2 = fmaxf(1.f - 2.f * dd + n02 * xk2, 1e-15f);
    const float nu2 = fmaxf(A2 * A2 * n02 - 2.f * A2 * B2 * dd + B2 * B2 * xk2, 0.f);
    const float mm2 = nu2 / (dn2 * dn2);
    float w = 0.f;
    if (mm2 < 0.101505f && mskme > 0.f) {
      const float dis = 2.f * artanh_c(sqrtf(fmaxf(mm2, 1e-14f)));
      w = fmaxf(1.f - dis * (1.0f / 0.66f), 0.f) * mskme;
    }
    const unsigned long long act = __ballot(w > 0.f);
    if (act == 0ull) {
      out[(size_t)b * DOUT + lane] = 0.f;
      continue;
    }
    const float xbd = x[(size_t)b * DIN + lane];
    float midv[KK];
#pragma unroll
    for (int k = 0; k < KK; ++k) {
      float macc = 0.f, wsm = 0.f;
      unsigned long long m = act & (0x1111111111111111ull << k);
      const float ebt = sEB[k][lane];
      const float eb2 = sEB2[k];
      while (m) {
        const int g = __ffsll(m) - 1;
        m &= m - 1;
        const float wn = __shfl(w, g, 64);
        const float fac_n = __shfl(fac, g, 64);
        const float A_n = __shfl(A, g, 64);
        const float n02_n = __shfl(n02, g, 64);
        const int j_n = __shfl(jc, g, 64);
        const float yd = x[(size_t)j_n * DIN + lane];
        const float x0t = fac_n * (Bc * yd - A_n * xbd);
        const float n0 = sqrtf(fmaxf(n02_n, 1e-14f));
        const float al = artanh_c(n0) / n0;
        asm volatile("s_waitcnt lgkmcnt(0)" ::: "memory");
        sUv[wv][lane] = al * x0t;
        asm volatile("s_waitcnt lgkmcnt(0)" ::: "memory");
        __builtin_amdgcn_sched_barrier(0);
        float a0 = 0.f, a1 = 0.f, a2 = 0.f, a3 = 0.f;
        const float4* wrow = reinterpret_cast<const float4*>(Wg) + ((k * DOUT + lane) << 4);
        const float4* urow = reinterpret_cast<const float4*>(&sUv[wv][0]);
#pragma unroll
        for (int g4 = 0; g4 < 16; ++g4) {
          const float4 w4 = wrow[g4];
          const float4 u4 = urow[g4];
          a0 = fmaf(w4.x, u4.x, a0);
          a1 = fmaf(w4.y, u4.y, a1);
          a2 = fmaf(w4.z, u4.z, a2);
          a3 = fmaf(w4.w, u4.w, a3);
        }
        const float hpre = (a0 + a1) + (a2 + a3);
        const float nh2 = wave_bcast_sum(hpre * hpre);
        const float nh = sqrtf(fmaxf(nh2, 1e-14f));
        const float sh = tanhf(nh) / nh;
        const float ht = sh * hpre;
        const float hx2 = sh * sh * nh2;
        const float hxy = wave_bcast_sum(ht * ebt);
        const float A3 = 1.f + 2.f * hxy + eb2;
        const float B3 = 1.f - hx2;
        const float dn3 = fmaxf(1.f + 2.f * hxy + hx2 * eb2, 1e-15f);
        float hm = (A3 * ht + B3 * ebt) / dn3;
        float n2h = wave_bcast_sum(hm * hm);
        const float nnh = sqrtf(fmaxf(n2h, 1e-14f));
        if (nnh > 0.99999f) {
          const float s = 0.99999f / nnh;
          hm *= s;
          n2h *= s * s;
        }
        const float ip = 1.f / (1.f + n2h);
        const float kx = 2.f * hm * ip;
        const float kx2 = 4.f * n2h * ip * ip;
        const float gam = 1.f / sqrtf(fmaxf(1.f - kx2, 1e-7f));
        const float wgv = wn * gam;
        macc = fmaf(wgv, kx, macc);
        wsm += wgv;
      }
      midv[k] = macc / fmaxf(wsm, 1e-10f);
    }
    float m2v[KK];
#pragma unroll
    for (int k = 0; k < KK; ++k) m2v[k] = midv[k] * midv[k];
#pragma unroll
    for (int s = 1; s < 64; s <<= 1) {
#pragma unroll
      for (int k = 0; k < KK; ++k) m2v[k] += __shfl_xor(m2v[k], s, 64);
    }
    float onum = 0.f, oden = 0.f;
#pragma unroll
    for (int k = 0; k < KK; ++k) {
      const float g = 1.f / sqrtf(fmaxf(1.f - m2v[k], 1e-7f));
      onum = fmaf(g, midv[k], onum);
      oden += g;
    }
    const float ok = onum / fmaxf(oden, 1e-10f);
    const float no2 = wave_bcast_sum(ok * ok);
    float p = ok / (1.f + sqrtf(fmaxf(1.f - no2, 1e-7f)));
    float np2 = wave_bcast_sum(p * p);
    float npn = sqrtf(fmaxf(np2, 1e-14f));
    if (npn > 0.99999f) {
      p *= 0.99999f / npn;
      npn = 0.99999f;
    }
    const float al2 = artanh_c(npn) / npn;
    const float rr = fmaxf(al2 * p, 0.f);
    const float nr2 = wave_bcast_sum(rr * rr);
    const float nrr = sqrtf(fmaxf(nr2, 1e-14f));
    out[(size_t)b * DOUT + lane] = tanhf(nrr) / nrr * rr;
  }
}

extern "C" void kernel_launch(void* const* d_in, const int* in_sizes, int n_in,
                              void* d_out, int out_size, void* d_ws, size_t ws_size,
                              hipStream_t stream) {
  const float* x = (const float*)d_in[0];
  const int* nei = (const int*)d_in[1];
  const float* nmask = (const float*)d_in[2];
  const float* W = (const float*)d_in[3];
  const float* bias = (const float*)d_in[4];
  const float* kt = (const float*)d_in[5];
  float* out = (float*)d_out;

  const int npts = in_sizes[0] / DIN;
  const size_t xh_bytes = (size_t)npts * DIN * sizeof(__half);
  const size_t need = xh_bytes + (size_t)npts * sizeof(float);

  int grid = (npts + WPB - 1) / WPB;
  if (grid > MAXBLOCKS) grid = MAXBLOCKS;

  if (d_ws != nullptr && ws_size >= need) {
    __half* xh = (__half*)d_ws;
    float* n2 = (float*)((char*)d_ws + xh_bytes);
    kpa_prep<<<grid, BLK, 0, stream>>>(x, xh, n2, npts);
    kpa_main<<<grid, BLK, 0, stream>>>(x, nei, nmask, W, bias, kt, xh, n2, out, npts);
  } else {
    kpa_fused<<<grid, BLK, 0, stream>>>(x, nei, nmask, W, bias, kt, out, npts);
  }
}

// Round 11
// 25.010 us; speedup vs baseline: 1.1610x; 1.0788x over previous
//
#include <hip/hip_runtime.h>

#define NEI 16
#define KK 4
#define DIN 64
#define DOUT 64
#define WPB 8
#define BLK (WPB * 64)
#define MAXBLOCKS 2048

__device__ __forceinline__ float wave_bcast_sum(float v) {
#pragma unroll
  for (int s = 1; s < 64; s <<= 1) v += __shfl_xor(v, s, 64);
  return v;
}

__device__ __forceinline__ float artanh_c(float z) {
  z = fminf(z, 1.0f - 1e-7f);
  z = fmaxf(z, -1.0f + 1e-7f);
  return atanhf(z);
}

// fast tanh for r >= 0 (v_exp_f32 based, ~1e-7 rel err)
__device__ __forceinline__ float tanh_fast(float r) {
  const float e = __expf(2.f * r);
  return (e - 1.f) / (e + 1.f);
}

__device__ __forceinline__ float cosh_fast(float t) {
  const float e = __expf(t);
  return 0.5f * (e + 1.f / e);
}

// Balanced persistent waves: grid = ceil(npts/16) -> each wave owns exactly
// 2 points (npts=20000: 1250 blocks x 8 waves x 2). Staging amortized over
// 16 points/block. Zero-store issues before the gate math (independent).
// Pregate (exact, monotone): dist(x,y) < 0.68+2*maxAT
//   <=> |x-y|^2 < Cthr*(1-|x|^2)(1-|y|^2), Cthr=(cosh(0.68+2*maxAT)-1)/2.
// Rare path: exact per-(n,k) gate + full pipeline (identical math to R7).
__global__ __launch_bounds__(BLK) void kpa_fused(
    const float* __restrict__ x, const int* __restrict__ nei,
    const float* __restrict__ nmask, const float* __restrict__ Wg,
    const float* __restrict__ bias, const float* __restrict__ kt,
    float* __restrict__ out, int npts) {
  __shared__ __align__(16) float sXK[KK][DIN];
  __shared__ __align__(16) float sEB[KK][DOUT];
  __shared__ float sXK2[KK], sEB2[KK], sAT[KK];
  __shared__ __align__(16) float sUv[WPB][DIN];

  const int tid = threadIdx.x, wv = tid >> 6, lane = tid & 63;

  // staging: waves 0..3 -> x_kernel[wv]=expmap0(kt); waves 4..7 -> expmap0(bias)
  if (wv < KK) {
    float v = kt[wv * DIN + lane];
    float n2 = wave_bcast_sum(v * v);
    float nr = sqrtf(fmaxf(n2, 1e-14f));
    float t = tanh_fast(nr);
    sXK[wv][lane] = t / nr * v;
    if (lane == 0) {
      sXK2[wv] = t * t;  // |expmap0(kt)|^2 = tanh(|kt|)^2
      sAT[wv] = nr;      // artanh|x_kernel| = |kt|
    }
  } else {
    const int k = wv - KK;
    float bv = bias[k * DOUT + lane];
    float bn2 = wave_bcast_sum(bv * bv);
    float bnr = sqrtf(fmaxf(bn2, 1e-14f));
    float tb = tanh_fast(bnr);
    sEB[k][lane] = tb / bnr * bv;
    if (lane == 0) sEB2[k] = tb * tb;
  }
  __syncthreads();

  const float maxAT = fmaxf(fmaxf(sAT[0], sAT[1]), fmaxf(sAT[2], sAT[3]));
  const float Cthr = 0.5f * (cosh_fast(0.68f + 2.f * maxAT) - 1.f);

  const int nn = lane >> 2, q = lane & 3, kme = lane & 3;
  const int stride = gridDim.x * WPB;

  int b = blockIdx.x * WPB + wv;
  if (b >= npts) return;
  int jc = nei[b * NEI + nn];

  for (;;) {
    const int bnext = b + stride;
    int jnext = 0;
    if (bnext < npts) jnext = nei[bnext * NEI + nn];  // prefetch next nei

    // gather current rows (segment-minimal interleave: float4 #(c*4+q))
    float4 yc[4], xc[4];
    {
      const float4* yr = reinterpret_cast<const float4*>(x + (size_t)jc * DIN);
      const float4* xr = reinterpret_cast<const float4*>(x + (size_t)b * DIN);
#pragma unroll
      for (int c = 0; c < 4; ++c) {
        xc[c] = xr[c * 4 + q];
        yc[c] = yr[c * 4 + q];
      }
    }
    // early zero-store: independent of the loads/gate, retires in background;
    // rare path (below) overwrites with the real value (same wave, prog order)
    out[(size_t)b * DOUT + lane] = 0.f;

    // local partial dots
    float xy = 0.f, y2 = 0.f, x2 = 0.f;
#pragma unroll
    for (int c = 0; c < 4; ++c) {
      xy = fmaf(yc[c].x, xc[c].x, xy); xy = fmaf(yc[c].y, xc[c].y, xy);
      xy = fmaf(yc[c].z, xc[c].z, xy); xy = fmaf(yc[c].w, xc[c].w, xy);
      y2 = fmaf(yc[c].x, yc[c].x, y2); y2 = fmaf(yc[c].y, yc[c].y, y2);
      y2 = fmaf(yc[c].z, yc[c].z, y2); y2 = fmaf(yc[c].w, yc[c].w, y2);
      x2 = fmaf(xc[c].x, xc[c].x, x2); x2 = fmaf(xc[c].y, xc[c].y, x2);
      x2 = fmaf(xc[c].z, xc[c].z, x2); x2 = fmaf(xc[c].w, xc[c].w, x2);
    }
#pragma unroll
    for (int s = 1; s < 4; s <<= 1) {
      xy += __shfl_xor(xy, s, 64);
      y2 += __shfl_xor(y2, s, 64);
      x2 += __shfl_xor(x2, s, 64);
    }

    // division-free pregate: |x-y|^2 < Cthr*(1-x2)*(1-y2)
    const float e2 = fmaxf(x2 - 2.f * xy + y2, 0.f);
    const bool nearp = e2 < Cthr * (1.f - x2) * (1.f - y2);

    if (__ballot(nearp) != 0ull) {
      // ---- rare path: exact gate (identical math to round 7) ----
      const float Bc = 1.f - x2;
      const float A = 1.f - 2.f * xy + y2;
      const float den = fmaxf(1.f - 2.f * xy + x2 * y2, 1e-15f);
      const float inv = 1.f / den;
      const float num2 = fmaxf(A * A * x2 - 2.f * A * Bc * xy + Bc * Bc * y2, 0.f);
      const float nm2 = num2 * inv * inv;

      const float mskme = nmask[b * NEI + nn];
      float dk[KK] = {0.f, 0.f, 0.f, 0.f};
      float pk[KK] = {0.f, 0.f, 0.f, 0.f};
#pragma unroll
      for (int k = 0; k < KK; ++k) {
        const float4* xkp = reinterpret_cast<const float4*>(&sXK[k][0]);
#pragma unroll
        for (int c = 0; c < 4; ++c) {
          const float4 xk4 = xkp[c * 4 + q];
          dk[k] = fmaf(yc[c].x, xk4.x, dk[k]); dk[k] = fmaf(yc[c].y, xk4.y, dk[k]);
          dk[k] = fmaf(yc[c].z, xk4.z, dk[k]); dk[k] = fmaf(yc[c].w, xk4.w, dk[k]);
          pk[k] = fmaf(xc[c].x, xk4.x, pk[k]); pk[k] = fmaf(xc[c].y, xk4.y, pk[k]);
          pk[k] = fmaf(xc[c].z, xk4.z, pk[k]); pk[k] = fmaf(xc[c].w, xk4.w, pk[k]);
        }
      }
#pragma unroll
      for (int s = 1; s < 4; s <<= 1) {
#pragma unroll
        for (int k = 0; k < KK; ++k) {
          dk[k] += __shfl_xor(dk[k], s, 64);
          pk[k] += __shfl_xor(pk[k], s, 64);
        }
      }

      const float nmr = sqrtf(fmaxf(nm2, 1e-14f));
      const float scl = (nmr > 0.99999f) ? (0.99999f / nmr) : 1.f;
      const float fac = inv * scl;
      const float n02 = nm2 * scl * scl;
      const float B2 = 1.f - n02;
      const float dd = fac * (Bc * dk[kme] - A * pk[kme]);
      const float xk2 = sXK2[kme];
      const float A2 = 1.f - 2.f * dd + xk2;
      const float dn2 = fmaxf(1.f - 2.f * dd + n02 * xk2, 1e-15f);
      const float nu2 = fmaxf(A2 * A2 * n02 - 2.f * A2 * B2 * dd + B2 * B2 * xk2, 0.f);
      const float mm2 = nu2 / (dn2 * dn2);
      float w = 0.f;
      if (mm2 < 0.101505f && mskme > 0.f) {  // tanh(0.33)^2 gate
        const float dis = 2.f * artanh_c(sqrtf(fmaxf(mm2, 1e-14f)));
        w = fmaxf(1.f - dis * (1.0f / 0.66f), 0.f) * mskme;
      }
      const unsigned long long act = __ballot(w > 0.f);
      if (act != 0ull) {
        // full per-(k,n) pipeline, vector over lane=d
        const float xbd = x[(size_t)b * DIN + lane];
        float midv[KK];
#pragma unroll
        for (int k = 0; k < KK; ++k) {
          float macc = 0.f, wsm = 0.f;
          unsigned long long m = act & (0x1111111111111111ull << k);
          const float ebt = sEB[k][lane];
          const float eb2 = sEB2[k];
          while (m) {
            const int g = __ffsll(m) - 1;
            m &= m - 1;
            const float wn = __shfl(w, g, 64);
            const float fac_n = __shfl(fac, g, 64);
            const float A_n = __shfl(A, g, 64);
            const float n02_n = __shfl(n02, g, 64);
            const int j_n = __shfl(jc, g, 64);
            const float yd = x[(size_t)j_n * DIN + lane];
            const float x0t = fac_n * (Bc * yd - A_n * xbd);
            const float n0 = sqrtf(fmaxf(n02_n, 1e-14f));
            const float al = artanh_c(n0) / n0;
            asm volatile("s_waitcnt lgkmcnt(0)" ::: "memory");
            sUv[wv][lane] = al * x0t;  // u = logmap0(x0)
            asm volatile("s_waitcnt lgkmcnt(0)" ::: "memory");
            __builtin_amdgcn_sched_barrier(0);
            // h_pre[o=lane] = sum_d W[k][o][d] * u[d]; W from global (L2-hot)
            float a0 = 0.f, a1 = 0.f, a2 = 0.f, a3 = 0.f;
            const float4* wrow = reinterpret_cast<const float4*>(Wg) + ((k * DOUT + lane) << 4);
            const float4* urow = reinterpret_cast<const float4*>(&sUv[wv][0]);
#pragma unroll
            for (int g4 = 0; g4 < 16; ++g4) {
              const float4 w4 = wrow[g4];
              const float4 u4 = urow[g4];
              a0 = fmaf(w4.x, u4.x, a0);
              a1 = fmaf(w4.y, u4.y, a1);
              a2 = fmaf(w4.z, u4.z, a2);
              a3 = fmaf(w4.w, u4.w, a3);
            }
            const float hpre = (a0 + a1) + (a2 + a3);
            const float nh2 = wave_bcast_sum(hpre * hpre);
            const float nh = sqrtf(fmaxf(nh2, 1e-14f));
            const float sh = tanhf(nh) / nh;
            const float ht = sh * hpre;              // h = expmap0(h_pre)
            const float hx2 = sh * sh * nh2;
            const float hxy = wave_bcast_sum(ht * ebt);
            const float A3 = 1.f + 2.f * hxy + eb2;  // proj(mobius_add(h, eb))
            const float B3 = 1.f - hx2;
            const float dn3 = fmaxf(1.f + 2.f * hxy + hx2 * eb2, 1e-15f);
            float hm = (A3 * ht + B3 * ebt) / dn3;
            float n2h = wave_bcast_sum(hm * hm);
            const float nnh = sqrtf(fmaxf(n2h, 1e-14f));
            if (nnh > 0.99999f) {
              const float s = 0.99999f / nnh;
              hm *= s;
              n2h *= s * s;
            }
            const float ip = 1.f / (1.f + n2h);      // kx = p2k(hm), gamma
            const float kx = 2.f * hm * ip;
            const float kx2 = 4.f * n2h * ip * ip;
            const float gam = 1.f / sqrtf(fmaxf(1.f - kx2, 1e-7f));
            const float wgv = wn * gam;
            macc = fmaf(wgv, kx, macc);
            wsm += wgv;
          }
          midv[k] = macc / fmaxf(wsm, 1e-10f);
        }

        float m2v[KK];
#pragma unroll
        for (int k = 0; k < KK; ++k) m2v[k] = midv[k] * midv[k];
#pragma unroll
        for (int s = 1; s < 64; s <<= 1) {
#pragma unroll
          for (int k = 0; k < KK; ++k) m2v[k] += __shfl_xor(m2v[k], s, 64);
        }
        float onum = 0.f, oden = 0.f;
#pragma unroll
        for (int k = 0; k < KK; ++k) {
          const float g = 1.f / sqrtf(fmaxf(1.f - m2v[k], 1e-7f));
          onum = fmaf(g, midv[k], onum);
          oden += g;
        }
        const float ok = onum / fmaxf(oden, 1e-10f);
        const float no2 = wave_bcast_sum(ok * ok);
        float p = ok / (1.f + sqrtf(fmaxf(1.f - no2, 1e-7f)));
        float np2 = wave_bcast_sum(p * p);
        float npn = sqrtf(fmaxf(np2, 1e-14f));
        if (npn > 0.99999f) {
          p *= 0.99999f / npn;
          npn = 0.99999f;
        }
        const float al2 = artanh_c(npn) / npn;
        const float rr = fmaxf(al2 * p, 0.f);
        const float nr2 = wave_bcast_sum(rr * rr);
        const float nrr = sqrtf(fmaxf(nr2, 1e-14f));
        out[(size_t)b * DOUT + lane] = tanhf(nrr) / nrr * rr;
      }
    }

    if (bnext >= npts) break;
    b = bnext;
    jc = jnext;
  }
}

extern "C" void kernel_launch(void* const* d_in, const int* in_sizes, int n_in,
                              void* d_out, int out_size, void* d_ws, size_t ws_size,
                              hipStream_t stream) {
  const float* x = (const float*)d_in[0];
  const int* nei = (const int*)d_in[1];
  const float* nmask = (const float*)d_in[2];
  const float* W = (const float*)d_in[3];
  const float* bias = (const float*)d_in[4];
  const float* kt = (const float*)d_in[5];
  float* out = (float*)d_out;

  const int npts = in_sizes[0] / DIN;
  // balanced: each wave owns exactly 2 points (npts=20000 -> 1250 blocks)
  int grid = (npts + 2 * WPB - 1) / (2 * WPB);
  if (grid < 1) grid = 1;
  if (grid > MAXBLOCKS) grid = MAXBLOCKS;
  kpa_fused<<<grid, BLK, 0, stream>>>(x, nei, nmask, W, bias, kt, out, npts);
}

// Round 12
// 21.338 us; speedup vs baseline: 1.3608x; 1.1721x over previous
//
#include <hip/hip_runtime.h>

#define NEI 16
#define KK 4
#define DIN 64
#define DOUT 64
#define WPB 4
#define BLK (WPB * 64)
#define MAXBLOCKS 2048

__device__ __forceinline__ float wave_bcast_sum(float v) {
#pragma unroll
  for (int s = 1; s < 64; s <<= 1) v += __shfl_xor(v, s, 64);
  return v;
}

__device__ __forceinline__ float artanh_c(float z) {
  z = fminf(z, 1.0f - 1e-7f);
  z = fmaxf(z, -1.0f + 1e-7f);
  return atanhf(z);
}

// fast tanh for r >= 0 (v_exp_f32 based, ~1e-7 rel err)
__device__ __forceinline__ float tanh_fast(float r) {
  const float e = __expf(2.f * r);
  return (e - 1.f) / (e + 1.f);
}

__device__ __forceinline__ float cosh_fast(float t) {
  const float e = __expf(t);
  return 0.5f * (e + 1.f / e);
}

// R7 structure (session best, 22.3us) + early zero-store (R11's one sound micro).
// Persistent waves, WPB=4/256-thread blocks, 2048-block grid.
// Common path per point: prefetched nei -> segment-minimal 16-row gather ->
//   early zero-store -> 3 quad-dots -> cosh-identity pregate -> done.
// Pregate (exact, monotone): dist(x,y) < 0.68+2*maxAT
//   <=> |x-y|^2 < Cthr*(1-|x|^2)(1-|y|^2), Cthr=(cosh(0.68+2*maxAT)-1)/2.
// Rare path: exact per-(n,k) gate + full pipeline (identical math to R7).
__global__ __launch_bounds__(BLK) void kpa_fused(
    const float* __restrict__ x, const int* __restrict__ nei,
    const float* __restrict__ nmask, const float* __restrict__ Wg,
    const float* __restrict__ bias, const float* __restrict__ kt,
    float* __restrict__ out, int npts) {
  __shared__ __align__(16) float sXK[KK][DIN];
  __shared__ __align__(16) float sEB[KK][DOUT];
  __shared__ float sXK2[KK], sEB2[KK], sAT[KK];
  __shared__ __align__(16) float sUv[WPB][DIN];

  const int tid = threadIdx.x, wv = tid >> 6, lane = tid & 63;

  // stage x_kernel[wv] = expmap0(kt[wv]), eb[wv] = expmap0(bias[wv])  (WPB==KK)
  {
    float v = kt[wv * DIN + lane];
    float bv = bias[wv * DOUT + lane];
    float n2 = wave_bcast_sum(v * v);
    float nr = sqrtf(fmaxf(n2, 1e-14f));
    float t = tanh_fast(nr);
    sXK[wv][lane] = t / nr * v;
    float bn2 = wave_bcast_sum(bv * bv);
    float bnr = sqrtf(fmaxf(bn2, 1e-14f));
    float tb = tanh_fast(bnr);
    sEB[wv][lane] = tb / bnr * bv;
    if (lane == 0) {
      sXK2[wv] = t * t;  // |expmap0(kt)|^2 = tanh(|kt|)^2
      sEB2[wv] = tb * tb;
      sAT[wv] = nr;      // artanh(|x_kernel|) = |kt| exactly
    }
  }
  __syncthreads();

  // pregate: dist(x,y) must be < 0.66 + 2*maxAT (+0.02 margin), via cosh identity
  const float maxAT = fmaxf(fmaxf(sAT[0], sAT[1]), fmaxf(sAT[2], sAT[3]));
  const float Cthr = 0.5f * (cosh_fast(0.68f + 2.f * maxAT) - 1.f);

  const int nn = lane >> 2, q = lane & 3, kme = lane & 3;
  const int stride = gridDim.x * WPB;

  int b = blockIdx.x * WPB + wv;
  if (b >= npts) return;
  int jcur = nei[b * NEI + nn];

  for (;;) {
    const int bnext = b + stride;
    int jnext = 0;
    if (bnext < npts) jnext = nei[bnext * NEI + nn];  // prefetch next nei

    // 16 dims per lane, interleaved chunks: float4 index c*4+q of each row
    float4 y4[4], xb4[4];
    {
      const float4* yrow = reinterpret_cast<const float4*>(x + (size_t)jcur * DIN);
      const float4* xrow = reinterpret_cast<const float4*>(x + (size_t)b * DIN);
#pragma unroll
      for (int c = 0; c < 4; ++c) {
        xb4[c] = xrow[c * 4 + q];
        y4[c] = yrow[c * 4 + q];
      }
    }
    // early zero-store: independent of the gate chain, retires in its shadow;
    // the rare path overwrites with the real value (same wave, program order)
    out[(size_t)b * DOUT + lane] = 0.f;

    // local partial dots
    float xy = 0.f, y2 = 0.f, x2 = 0.f;
#pragma unroll
    for (int c = 0; c < 4; ++c) {
      xy = fmaf(y4[c].x, xb4[c].x, xy); xy = fmaf(y4[c].y, xb4[c].y, xy);
      xy = fmaf(y4[c].z, xb4[c].z, xy); xy = fmaf(y4[c].w, xb4[c].w, xy);
      y2 = fmaf(y4[c].x, y4[c].x, y2); y2 = fmaf(y4[c].y, y4[c].y, y2);
      y2 = fmaf(y4[c].z, y4[c].z, y2); y2 = fmaf(y4[c].w, y4[c].w, y2);
      x2 = fmaf(xb4[c].x, xb4[c].x, x2); x2 = fmaf(xb4[c].y, xb4[c].y, x2);
      x2 = fmaf(xb4[c].z, xb4[c].z, x2); x2 = fmaf(xb4[c].w, xb4[c].w, x2);
    }
#pragma unroll
    for (int s = 1; s < 4; s <<= 1) {
      xy += __shfl_xor(xy, s, 64);
      y2 += __shfl_xor(y2, s, 64);
      x2 += __shfl_xor(x2, s, 64);
    }

    // division-free pregate: |x-y|^2 < Cthr*(1-x2)*(1-y2)
    const float e2 = fmaxf(x2 - 2.f * xy + y2, 0.f);
    const bool nearp = e2 < Cthr * (1.f - x2) * (1.f - y2);

    if (__ballot(nearp) != 0ull) {  // rare: some neighbor hyperbolically near
      // ---- exact gate (identical math to round 7) ----
      const float Bc = 1.f - x2;
      const float A = 1.f - 2.f * xy + y2;
      const float den = fmaxf(1.f - 2.f * xy + x2 * y2, 1e-15f);
      const float inv = 1.f / den;
      const float num2 = fmaxf(A * A * x2 - 2.f * A * Bc * xy + Bc * Bc * y2, 0.f);
      const float nm2 = num2 * inv * inv;

      const float mskme = nmask[b * NEI + nn];
      float dk[KK] = {0.f, 0.f, 0.f, 0.f};  // y . xk[k]
      float pk[KK] = {0.f, 0.f, 0.f, 0.f};  // xb . xk[k]
#pragma unroll
      for (int k = 0; k < KK; ++k) {
        const float4* xkp = reinterpret_cast<const float4*>(&sXK[k][0]);
#pragma unroll
        for (int c = 0; c < 4; ++c) {
          const float4 xk4 = xkp[c * 4 + q];
          dk[k] = fmaf(y4[c].x, xk4.x, dk[k]); dk[k] = fmaf(y4[c].y, xk4.y, dk[k]);
          dk[k] = fmaf(y4[c].z, xk4.z, dk[k]); dk[k] = fmaf(y4[c].w, xk4.w, dk[k]);
          pk[k] = fmaf(xb4[c].x, xk4.x, pk[k]); pk[k] = fmaf(xb4[c].y, xk4.y, pk[k]);
          pk[k] = fmaf(xb4[c].z, xk4.z, pk[k]); pk[k] = fmaf(xb4[c].w, xk4.w, pk[k]);
        }
      }
#pragma unroll
      for (int s = 1; s < 4; s <<= 1) {
#pragma unroll
        for (int k = 0; k < KK; ++k) {
          dk[k] += __shfl_xor(dk[k], s, 64);
          pk[k] += __shfl_xor(pk[k], s, 64);
        }
      }

      const float nmr = sqrtf(fmaxf(nm2, 1e-14f));
      const float scl = (nmr > 0.99999f) ? (0.99999f / nmr) : 1.f;
      const float fac = inv * scl;
      const float n02 = nm2 * scl * scl;
      const float B2 = 1.f - n02;
      const float dd = fac * (Bc * dk[kme] - A * pk[kme]);  // x0 . x_kernel[k]
      const float xk2 = sXK2[kme];
      const float A2 = 1.f - 2.f * dd + xk2;
      const float dn2 = fmaxf(1.f - 2.f * dd + n02 * xk2, 1e-15f);
      const float nu2 = fmaxf(A2 * A2 * n02 - 2.f * A2 * B2 * dd + B2 * B2 * xk2, 0.f);
      const float mm2 = nu2 / (dn2 * dn2);
      float w = 0.f;
      if (mm2 < 0.101505f && mskme > 0.f) {  // tanh(0.33)^2 gate
        const float dis = 2.f * artanh_c(sqrtf(fmaxf(mm2, 1e-14f)));
        w = fmaxf(1.f - dis * (1.0f / 0.66f), 0.f) * mskme;
      }
      const unsigned long long act = __ballot(w > 0.f);
      if (act != 0ull) {
        // full per-(k,n) pipeline, vector over lane=d
        const float xbd = x[(size_t)b * DIN + lane];
        float midv[KK];
#pragma unroll
        for (int k = 0; k < KK; ++k) {
          float macc = 0.f, wsm = 0.f;
          unsigned long long m = act & (0x1111111111111111ull << k);
          const float ebt = sEB[k][lane];
          const float eb2 = sEB2[k];
          while (m) {
            const int g = __ffsll(m) - 1;
            m &= m - 1;
            const float wn = __shfl(w, g, 64);
            const float fac_n = __shfl(fac, g, 64);
            const float A_n = __shfl(A, g, 64);
            const float n02_n = __shfl(n02, g, 64);
            const int j_n = __shfl(jcur, g, 64);
            const float yd = x[(size_t)j_n * DIN + lane];
            const float x0t = fac_n * (Bc * yd - A_n * xbd);
            const float n0 = sqrtf(fmaxf(n02_n, 1e-14f));
            const float al = artanh_c(n0) / n0;
            asm volatile("s_waitcnt lgkmcnt(0)" ::: "memory");
            sUv[wv][lane] = al * x0t;  // u = logmap0(x0)
            asm volatile("s_waitcnt lgkmcnt(0)" ::: "memory");
            __builtin_amdgcn_sched_barrier(0);
            // h_pre[o=lane] = sum_d W[k][o][d] * u[d]; W from global (L2-hot)
            float a0 = 0.f, a1 = 0.f, a2 = 0.f, a3 = 0.f;
            const float4* wrow = reinterpret_cast<const float4*>(Wg) + ((k * DOUT + lane) << 4);
            const float4* urow = reinterpret_cast<const float4*>(&sUv[wv][0]);
#pragma unroll
            for (int g4 = 0; g4 < 16; ++g4) {
              const float4 w4 = wrow[g4];
              const float4 u4 = urow[g4];
              a0 = fmaf(w4.x, u4.x, a0);
              a1 = fmaf(w4.y, u4.y, a1);
              a2 = fmaf(w4.z, u4.z, a2);
              a3 = fmaf(w4.w, u4.w, a3);
            }
            const float hpre = (a0 + a1) + (a2 + a3);
            const float nh2 = wave_bcast_sum(hpre * hpre);
            const float nh = sqrtf(fmaxf(nh2, 1e-14f));
            const float sh = tanhf(nh) / nh;
            const float ht = sh * hpre;              // h = expmap0(h_pre)
            const float hx2 = sh * sh * nh2;
            const float hxy = wave_bcast_sum(ht * ebt);
            const float A3 = 1.f + 2.f * hxy + eb2;  // proj(mobius_add(h, eb))
            const float B3 = 1.f - hx2;
            const float dn3 = fmaxf(1.f + 2.f * hxy + hx2 * eb2, 1e-15f);
            float hm = (A3 * ht + B3 * ebt) / dn3;
            float n2h = wave_bcast_sum(hm * hm);
            const float nnh = sqrtf(fmaxf(n2h, 1e-14f));
            if (nnh > 0.99999f) {
              const float s = 0.99999f / nnh;
              hm *= s;
              n2h *= s * s;
            }
            const float ip = 1.f / (1.f + n2h);      // kx = p2k(hm), gamma
            const float kx = 2.f * hm * ip;
            const float kx2 = 4.f * n2h * ip * ip;
            const float gam = 1.f / sqrtf(fmaxf(1.f - kx2, 1e-7f));
            const float wgv = wn * gam;
            macc = fmaf(wgv, kx, macc);
            wsm += wgv;
          }
          midv[k] = macc / fmaxf(wsm, 1e-10f);
        }

        float m2v[KK];
#pragma unroll
        for (int k = 0; k < KK; ++k) m2v[k] = midv[k] * midv[k];
#pragma unroll
        for (int s = 1; s < 64; s <<= 1) {
#pragma unroll
          for (int k = 0; k < KK; ++k) m2v[k] += __shfl_xor(m2v[k], s, 64);
        }
        float onum = 0.f, oden = 0.f;
#pragma unroll
        for (int k = 0; k < KK; ++k) {
          const float g = 1.f / sqrtf(fmaxf(1.f - m2v[k], 1e-7f));
          onum = fmaf(g, midv[k], onum);
          oden += g;
        }
        const float ok = onum / fmaxf(oden, 1e-10f);
        const float no2 = wave_bcast_sum(ok * ok);
        float p = ok / (1.f + sqrtf(fmaxf(1.f - no2, 1e-7f)));
        float np2 = wave_bcast_sum(p * p);
        float npn = sqrtf(fmaxf(np2, 1e-14f));
        if (npn > 0.99999f) {
          p *= 0.99999f / npn;
          npn = 0.99999f;
        }
        const float al2 = artanh_c(npn) / npn;
        const float rr = fmaxf(al2 * p, 0.f);
        const float nr2 = wave_bcast_sum(rr * rr);
        const float nrr = sqrtf(fmaxf(nr2, 1e-14f));
        out[(size_t)b * DOUT + lane] = tanhf(nrr) / nrr * rr;
      }
    }

    if (bnext >= npts) break;
    b = bnext;
    jcur = jnext;
  }
}

extern "C" void kernel_launch(void* const* d_in, const int* in_sizes, int n_in,
                              void* d_out, int out_size, void* d_ws, size_t ws_size,
                              hipStream_t stream) {
  const float* x = (const float*)d_in[0];
  const int* nei = (const int*)d_in[1];
  const float* nmask = (const float*)d_in[2];
  const float* W = (const float*)d_in[3];
  const float* bias = (const float*)d_in[4];
  const float* kt = (const float*)d_in[5];
  float* out = (float*)d_out;

  const int npts = in_sizes[0] / DIN;
  int grid = (npts + WPB - 1) / WPB;
  if (grid > MAXBLOCKS) grid = MAXBLOCKS;
  kpa_fused<<<grid, BLK, 0, stream>>>(x, nei, nmask, W, bias, kt, out, npts);
}